// Round 1
// baseline (1871.758 us; speedup 1.0000x reference)
//
#include <hip/hip_runtime.h>
#include <hip/hip_bf16.h>

// Problem constants
#define NB    4        // batch
#define HH    96
#define WW    96
#define PIX   9216     // 96*96
#define C0    324      // cor_planes
#define C1    256
#define C2    256
#define C3    128
#define MM    48       // detections per batch
#define NROI  192      // NB*MM
#define NPAIR 9216     // NB*MM*MM
#define RHW   7
#define KHEAD 6468     // 132*49
#define KRF   6272     // 128*49

// ---------------------------------------------------------------------------
// Generic transpose: w[O][K] -> wt[K][O]
__global__ __launch_bounds__(256) void transpose_kernel(
    const float* __restrict__ w, float* __restrict__ wt, int O, int K)
{
    long long idx = (long long)blockIdx.x * 256 + threadIdx.x;
    if (idx >= (long long)O * K) return;
    int k = (int)(idx / O);
    int o = (int)(idx % O);
    wt[idx] = w[(long long)o * K + k];
}

// ---------------------------------------------------------------------------
// wsum4[oc][j] = sum over 7x7 of head_w[oc][128+j][ky][kx]
__global__ __launch_bounds__(256) void wsum_kernel(
    const float* __restrict__ hw, float* __restrict__ wsum4)
{
    int idx = blockIdx.x * 256 + threadIdx.x;
    if (idx >= 256 * 4) return;
    int oc = idx >> 2, j = idx & 3;
    const float* p = hw + (long long)oc * KHEAD + (128 + j) * 49;
    float s = 0.f;
    #pragma unroll
    for (int t = 0; t < 49; ++t) s += p[t];
    wsum4[idx] = s;
}

// ---------------------------------------------------------------------------
// Tiled GEMM: out[b][o][n] = act(sum_k Wt[k][o] * Bmat[b][k][n] + bias[o])
// N fixed at 9216 (pixels or pairs). Tile 128x128, thread 8x8.
__global__ __launch_bounds__(256) void gemm128_bias_act(
    const float* __restrict__ Bmat,   // [batch][K][9216]
    const float* __restrict__ Wt,     // [K][O]
    const float* __restrict__ bias,   // [O]
    float* __restrict__ out,          // [batch][O][9216]
    int K, int O, int relu)
{
    const int KC = 4;
    __shared__ float As[KC][128];
    __shared__ float Bs[KC][128];
    const int tid = threadIdx.x;
    const int b   = blockIdx.z;
    const int p0  = blockIdx.x * 128;
    const int o0  = blockIdx.y * 128;
    const int to  = tid >> 4;   // 0..15
    const int tp  = tid & 15;   // 0..15
    const float* Bb = Bmat + (long long)b * K * PIX;

    float acc[8][8];
    #pragma unroll
    for (int i = 0; i < 8; ++i)
        #pragma unroll
        for (int j = 0; j < 8; ++j) acc[i][j] = 0.f;

    for (int k0 = 0; k0 < K; k0 += KC) {
        #pragma unroll
        for (int l = 0; l < 2; ++l) {
            int idx = tid + l * 256;       // 0..511
            int kc = idx >> 7, j = idx & 127;
            As[kc][j] = Wt[(long long)(k0 + kc) * O + o0 + j];
            Bs[kc][j] = Bb[(long long)(k0 + kc) * PIX + p0 + j];
        }
        __syncthreads();
        #pragma unroll
        for (int kc = 0; kc < KC; ++kc) {
            float a[8], bb[8];
            *(float4*)&a[0]  = *(const float4*)&As[kc][to * 8];
            *(float4*)&a[4]  = *(const float4*)&As[kc][to * 8 + 4];
            *(float4*)&bb[0] = *(const float4*)&Bs[kc][tp * 8];
            *(float4*)&bb[4] = *(const float4*)&Bs[kc][tp * 8 + 4];
            #pragma unroll
            for (int i = 0; i < 8; ++i)
                #pragma unroll
                for (int j = 0; j < 8; ++j)
                    acc[i][j] += a[i] * bb[j];
        }
        __syncthreads();
    }
    #pragma unroll
    for (int i = 0; i < 8; ++i) {
        int oc = o0 + to * 8 + i;
        float bv = bias[oc];
        #pragma unroll
        for (int j = 0; j < 8; ++j) {
            float v = acc[i][j] + bv;
            if (relu) v = fmaxf(v, 0.f);
            out[(long long)(b * O + oc) * PIX + p0 + tp * 8 + j] = v;
        }
    }
}

// ---------------------------------------------------------------------------
// 3x3 same-pad conv + relu. Tile: 64 oc x (4 rows x 32 cols). Thread: 4oc x 2r x 4c.
__global__ __launch_bounds__(256) void conv3x3_relu(
    const float* __restrict__ in,    // [N][Cin][96][96]
    const float* __restrict__ wt,    // [Cin*9][Cout]  (transposed weights)
    const float* __restrict__ bias,  // [Cout]
    float* __restrict__ out,         // [N][Cout][96][96]
    int Cin, int Cout)
{
    const int KC = 4;
    __shared__ float As[KC][9][64];
    __shared__ float Bs[KC][6][34];
    const int tid = threadIdx.x;
    const int b   = blockIdx.z;
    const int o0  = blockIdx.y * 64;
    const int tile = blockIdx.x;                // 0..71
    const int x0  = (tile % 3) * 32;
    const int y0  = (tile / 3) * 4;
    const int to  = tid >> 4;                   // 0..15 -> oc group
    const int tp  = tid & 15;
    const int rbase = (tp >> 3) * 2;            // 0 or 2
    const int cbase = (tp & 7) * 4;             // 0..28

    float acc[4][2][4];
    #pragma unroll
    for (int i = 0; i < 4; ++i)
        #pragma unroll
        for (int r = 0; r < 2; ++r)
            #pragma unroll
            for (int c = 0; c < 4; ++c) acc[i][r][c] = 0.f;

    const float* inb = in + (long long)b * Cin * PIX;

    for (int k0 = 0; k0 < Cin; k0 += KC) {
        // stage weights: KC*9*64 = 2304 elems, coalesced over o
        #pragma unroll
        for (int l = 0; l < 9; ++l) {
            int idx = tid + l * 256;
            int kc = idx / 576; int rem = idx % 576;
            int tap = rem >> 6; int o = rem & 63;
            As[kc][tap][o] = wt[(long long)((k0 + kc) * 9 + tap) * Cout + o0 + o];
        }
        // stage input halo tile: KC*6*34 = 816 elems
        for (int idx = tid; idx < KC * 6 * 34; idx += 256) {
            int kc = idx / 204; int rem = idx % 204;
            int r = rem / 34;  int c = rem % 34;
            int gy = y0 - 1 + r, gx = x0 - 1 + c;
            float v = 0.f;
            if (gy >= 0 && gy < HH && gx >= 0 && gx < WW)
                v = inb[(long long)(k0 + kc) * PIX + gy * WW + gx];
            Bs[kc][r][c] = v;
        }
        __syncthreads();
        #pragma unroll
        for (int kc = 0; kc < KC; ++kc) {
            float bw[4][6];
            #pragma unroll
            for (int r = 0; r < 4; ++r)
                #pragma unroll
                for (int c = 0; c < 6; ++c)
                    bw[r][c] = Bs[kc][rbase + r][cbase + c];
            #pragma unroll
            for (int dy = 0; dy < 3; ++dy)
                #pragma unroll
                for (int dx = 0; dx < 3; ++dx) {
                    const float4 a = *(const float4*)&As[kc][dy * 3 + dx][to * 4];
                    const float av[4] = {a.x, a.y, a.z, a.w};
                    #pragma unroll
                    for (int i = 0; i < 4; ++i)
                        #pragma unroll
                        for (int rr = 0; rr < 2; ++rr)
                            #pragma unroll
                            for (int cc = 0; cc < 4; ++cc)
                                acc[i][rr][cc] += av[i] * bw[rr + dy][cc + dx];
                }
        }
        __syncthreads();
    }
    #pragma unroll
    for (int i = 0; i < 4; ++i) {
        int oc = o0 + to * 4 + i;
        float bv = bias[oc];
        #pragma unroll
        for (int rr = 0; rr < 2; ++rr) {
            int y = y0 + rbase + rr;
            #pragma unroll
            for (int cc = 0; cc < 4; ++cc) {
                int x = x0 + cbase + cc;
                float v = acc[i][rr][cc] + bv;
                out[(long long)(b * Cout + oc) * PIX + y * WW + x] = v > 0.f ? v : 0.f;
            }
        }
    }
}

// ---------------------------------------------------------------------------
// ROI align: rel [4][128][96][96], det1 [4][48][10] -> rf [192][6272]
__global__ __launch_bounds__(256) void roi_align_kernel(
    const float* __restrict__ rel, const float* __restrict__ det1,
    float* __restrict__ rf)
{
    int roi = blockIdx.x;
    int idx = blockIdx.y * 256 + threadIdx.x;
    if (idx >= KRF) return;
    int c  = idx / 49;
    int ij = idx % 49;
    int i  = ij / 7, j = ij % 7;
    int b  = roi / MM, m = roi % MM;
    const float* d = det1 + (long long)(b * MM + m) * 10;
    float cx = d[2], cy = d[3], w = d[4], h = d[5];
    float x1f = (cx - w * 0.5f);
    float y1f = (cy - h * 0.5f);
    float x1 = x1f * 0.125f, y1 = y1f * 0.125f;
    float x2 = (x1f + w) * 0.125f, y2 = (y1f + h) * 0.125f;
    float bh = (y2 - y1) * (1.f / 7.f);
    float bw = (x2 - x1) * (1.f / 7.f);
    const float* f = rel + (long long)(b * C3 + c) * PIX;
    float s = 0.f;
    #pragma unroll
    for (int di = 0; di < 2; ++di) {
        float y = y1 + ((float)(2 * i + di) + 0.5f) * 0.5f * bh;
        y = fminf(fmaxf(y, 0.f), 95.f);
        int yy0 = (int)floorf(y);
        int yy1 = min(yy0 + 1, 95);
        float wy = y - (float)yy0;
        #pragma unroll
        for (int dj = 0; dj < 2; ++dj) {
            float x = x1 + ((float)(2 * j + dj) + 0.5f) * 0.5f * bw;
            x = fminf(fmaxf(x, 0.f), 95.f);
            int xx0 = (int)floorf(x);
            int xx1 = min(xx0 + 1, 95);
            float wx = x - (float)xx0;
            float f00 = f[yy0 * WW + xx0], f01 = f[yy0 * WW + xx1];
            float f10 = f[yy1 * WW + xx0], f11 = f[yy1 * WW + xx1];
            s += f00 * (1.f - wy) * (1.f - wx) + f01 * (1.f - wy) * wx
               + f10 * wy * (1.f - wx)        + f11 * wy * wx;
        }
    }
    rf[(long long)roi * KRF + idx] = s * 0.25f;
}

// ---------------------------------------------------------------------------
// Head GEMM: G[roi][oc] = sum_k rf[roi][k] * wtH[k][oc]   (k < 6272)
__global__ __launch_bounds__(256) void head_gemm_kernel(
    const float* __restrict__ rf, const float* __restrict__ wtH,
    float* __restrict__ G)
{
    __shared__ float R[KRF];
    const int roi = blockIdx.x;
    const int tid = threadIdx.x;
    for (int idx = tid; idx < KRF; idx += 256)
        R[idx] = rf[(long long)roi * KRF + idx];
    __syncthreads();
    float acc = 0.f;
    #pragma unroll 8
    for (int k = 0; k < KRF; ++k)
        acc += R[k] * wtH[(long long)k * 256 + tid];
    G[roi * 256 + tid] = acc;
}

// ---------------------------------------------------------------------------
// Per-pair geometry: pos4, labels, valid
__global__ __launch_bounds__(256) void pair_kernel(
    const float* __restrict__ d1, const float* __restrict__ d2,
    float* __restrict__ pos4, float* __restrict__ labels,
    float* __restrict__ valid)
{
    int pair = blockIdx.x * 256 + threadIdx.x;
    if (pair >= NPAIR) return;
    int b = pair / (MM * MM); int rem = pair % (MM * MM);
    int m1 = rem / MM, m2 = rem % MM;
    const float* r1 = d1 + (long long)(b * MM + m1) * 10;
    const float* r2 = d2 + (long long)(b * MM + m2) * 10;
    float v1 = r1[0], id1 = r1[1], cxa = r1[2], cya = r1[3], wa = r1[4], ha = r1[5];
    float v2 = r2[0], id2 = r2[1], cxb = r2[2], cyb = r2[3], wb = r2[4], hb = r2[5];
    const float eps = 1e-6f;
    // to_xyxy then back, faithfully
    float ax1 = cxa - wa * 0.5f, ay1 = cya - ha * 0.5f;
    float ax2 = ax1 + wa,        ay2 = ay1 + ha;
    float bx1 = cxb - wb * 0.5f, by1 = cyb - hb * 0.5f;
    float bx2 = bx1 + wb,        by2 = by1 + hb;
    float ccx1 = (ax1 + ax2) * 0.5f, ccy1 = (ay1 + ay2) * 0.5f;
    float ww1 = fmaxf(ax2 - ax1, eps), hh1 = fmaxf(ay2 - ay1, eps);
    float ccx2 = (bx1 + bx2) * 0.5f, ccy2 = (by1 + by2) * 0.5f;
    float ww2 = fmaxf(bx2 - bx1, eps), hh2 = fmaxf(by2 - by1, eps);
    pos4[pair * 4 + 0] = (ccx2 - ccx1) / ww1;
    pos4[pair * 4 + 1] = (ccy2 - ccy1) / hh1;
    pos4[pair * 4 + 2] = logf(ww2 / ww1);
    pos4[pair * 4 + 3] = logf(hh2 / hh1);
    labels[pair] = (id1 == id2) ? 1.f : 0.f;
    valid[pair]  = (v1 != -1.f && v2 != -1.f) ? 1.f : 0.f;
}

// ---------------------------------------------------------------------------
// X[oc][pair] = G[roi(pair)][oc] + pos4[pair].wsum4[oc] + head_b[oc]
__global__ __launch_bounds__(256) void build_X_kernel(
    const float* __restrict__ G, const float* __restrict__ pos4,
    const float* __restrict__ wsum4, const float* __restrict__ hb,
    float* __restrict__ X)
{
    int idx = blockIdx.x * 256 + threadIdx.x;   // 256*9216 exactly
    int oc = idx / NPAIR;
    int pair = idx % NPAIR;
    int roi = pair / MM;
    const float* p4 = pos4 + pair * 4;
    const float* w4 = wsum4 + oc * 4;
    float v = G[roi * 256 + oc] + hb[oc]
            + p4[0] * w4[0] + p4[1] * w4[1] + p4[2] * w4[2] + p4[3] * w4[3];
    X[(long long)oc * NPAIR + pair] = v;
}

// ---------------------------------------------------------------------------
// scores[pair] = sum_k cls_w[k] * H2[k][pair] + cls_b
__global__ __launch_bounds__(256) void cls_kernel(
    const float* __restrict__ H2, const float* __restrict__ cw,
    const float* __restrict__ cb, float* __restrict__ scores)
{
    __shared__ float w[256];
    int tid = threadIdx.x;
    w[tid] = cw[tid];
    __syncthreads();
    int pair = blockIdx.x * 256 + tid;
    float acc = cb[0];
    #pragma unroll 8
    for (int k = 0; k < 256; ++k)
        acc += w[k] * H2[(long long)k * NPAIR + pair];
    scores[pair] = acc;
}

// ---------------------------------------------------------------------------
extern "C" void kernel_launch(void* const* d_in, const int* in_sizes, int n_in,
                              void* d_out, int out_size, void* d_ws, size_t ws_size,
                              hipStream_t stream) {
    const float* corr   = (const float*)d_in[0];
    const float* det1   = (const float*)d_in[2];   // detection1 (index 1 is detection1_, unused)
    const float* det2   = (const float*)d_in[3];
    const float* c1w    = (const float*)d_in[4];
    const float* c1b    = (const float*)d_in[5];
    const float* c2w    = (const float*)d_in[6];
    const float* c2b    = (const float*)d_in[7];
    const float* c3w    = (const float*)d_in[8];
    const float* c3b    = (const float*)d_in[9];
    const float* hw     = (const float*)d_in[10];
    const float* hbias  = (const float*)d_in[11];
    const float* f6w    = (const float*)d_in[12];
    const float* f6b    = (const float*)d_in[13];
    const float* f7w    = (const float*)d_in[14];
    const float* f7b    = (const float*)d_in[15];
    const float* clsw   = (const float*)d_in[16];
    const float* clsb   = (const float*)d_in[17];
    float* out = (float*)d_out;

    // workspace layout (floats)
    float* ws = (float*)d_ws;
    long long off = 0;
    float* buf1  = ws + off; off += (long long)NB * C1 * PIX;   // c1 out, later rel (128ch)
    float* buf2  = ws + off; off += (long long)NB * C2 * PIX;   // c2 out
    float* wt1   = ws + off; off += (long long)C0 * C1;         // [324][256]
    float* wt2   = ws + off; off += (long long)C1 * 9 * C2;     // [2304][256]
    float* wt3   = ws + off; off += (long long)C2 * 9 * C3;     // [2304][128]
    float* wtH   = ws + off; off += (long long)KHEAD * 256;     // [6468][256]
    float* wtf6  = ws + off; off += 256 * 256;
    float* wtf7  = ws + off; off += 256 * 256;
    float* wsum4 = ws + off; off += 256 * 4;
    float* rf    = ws + off; off += (long long)NROI * KRF;
    float* G     = ws + off; off += NROI * 256;
    float* pos4  = ws + off; off += NPAIR * 4;
    float* X     = ws + off; off += (long long)256 * NPAIR;
    float* H1    = ws + off; off += (long long)256 * NPAIR;
    float* H2    = ws + off; off += (long long)256 * NPAIR;

    float* scores_out = out;
    float* labels_out = out + NPAIR;
    float* valid_out  = out + 2 * NPAIR;

    // 1. weight transposes
    auto tgrid = [](long long n) { return dim3((unsigned)((n + 255) / 256)); };
    transpose_kernel<<<tgrid((long long)C1 * C0), 256, 0, stream>>>(c1w, wt1, C1, C0);
    transpose_kernel<<<tgrid((long long)C2 * C1 * 9), 256, 0, stream>>>(c2w, wt2, C2, C1 * 9);
    transpose_kernel<<<tgrid((long long)C3 * C2 * 9), 256, 0, stream>>>(c3w, wt3, C3, C2 * 9);
    transpose_kernel<<<tgrid((long long)256 * KHEAD), 256, 0, stream>>>(hw, wtH, 256, KHEAD);
    transpose_kernel<<<tgrid(256 * 256), 256, 0, stream>>>(f6w, wtf6, 256, 256);
    transpose_kernel<<<tgrid(256 * 256), 256, 0, stream>>>(f7w, wtf7, 256, 256);
    wsum_kernel<<<dim3(4), 256, 0, stream>>>(hw, wsum4);

    // 2. conv1 (1x1, 324->256) as GEMM, batch=4
    gemm128_bias_act<<<dim3(PIX / 128, C1 / 128, NB), 256, 0, stream>>>(
        corr, wt1, c1b, buf1, C0, C1, 1);

    // 3. conv2 (3x3, 256->256)
    conv3x3_relu<<<dim3(72, C2 / 64, NB), 256, 0, stream>>>(buf1, wt2, c2b, buf2, C1, C2);

    // 4. conv3 (3x3, 256->128) -> rel in buf1
    conv3x3_relu<<<dim3(72, C3 / 64, NB), 256, 0, stream>>>(buf2, wt3, c3b, buf1, C2, C3);

    // 5. ROI align
    roi_align_kernel<<<dim3(NROI, (KRF + 255) / 256), 256, 0, stream>>>(buf1, det1, rf);

    // 6. head GEMM (per-ROI part)
    head_gemm_kernel<<<dim3(NROI), 256, 0, stream>>>(rf, wtH, G);

    // 7. per-pair geometry (+ labels/valid straight to output)
    pair_kernel<<<dim3(NPAIR / 256), 256, 0, stream>>>(det1, det2, pos4, labels_out, valid_out);

    // 8. assemble head-conv output X [256][9216]
    build_X_kernel<<<dim3(256 * NPAIR / 256), 256, 0, stream>>>(G, pos4, wsum4, hbias, X);

    // 9. fc6, fc7
    gemm128_bias_act<<<dim3(NPAIR / 128, 2, 1), 256, 0, stream>>>(X, wtf6, f6b, H1, 256, 256, 1);
    gemm128_bias_act<<<dim3(NPAIR / 128, 2, 1), 256, 0, stream>>>(H1, wtf7, f7b, H2, 256, 256, 1);

    // 10. classifier
    cls_kernel<<<dim3(NPAIR / 256), 256, 0, stream>>>(H2, clsw, clsb, scores_out);
}

// Round 2
// 407.856 us; speedup vs baseline: 4.5893x; 4.5893x over previous
//
#include <hip/hip_runtime.h>
#include <hip/hip_bf16.h>

// Problem constants
#define NB    4
#define HH    96
#define WW    96
#define PIX   9216
#define C0    324
#define MM    48
#define NROI  192
#define NPAIR 9216
#define KHEAD 6468
#define KRF   6272
#define SPLITS 14
#define CPS    14    // chunks per split: 14*14*32 = 6272

typedef unsigned short u16;
typedef __attribute__((ext_vector_type(8))) short bf16x8;
typedef __attribute__((ext_vector_type(4))) float f32x4;
typedef __attribute__((ext_vector_type(4))) unsigned short u16x4;
typedef __attribute__((ext_vector_type(4))) int i32x4;

__device__ __forceinline__ u16 f2bf(float f) {
    __hip_bfloat16 h = __float2bfloat16(f);
    union { __hip_bfloat16 h; u16 u; } c; c.h = h; return c.u;
}
__device__ __forceinline__ float b2f(u16 u) {
    union { unsigned int i; float f; } c; c.i = ((unsigned int)u) << 16; return c.f;
}

// ---------------------------------------------------------------------------
// zero a range of int4s
__global__ __launch_bounds__(256) void zero16_kernel(i32x4* __restrict__ p, long long n16)
{
    long long i = (long long)blockIdx.x * 256 + threadIdx.x;
    if (i < n16) { i32x4 z = {0,0,0,0}; p[i] = z; }
}

// ---------------------------------------------------------------------------
// conv1 weights [256][324] -> tiled [11][16 octile][16 m][32 kk] bf16, zero-pad k>=324
__global__ __launch_bounds__(256) void prep_wt1_kernel(
    const float* __restrict__ w, u16* __restrict__ wf)
{
    int idx = blockIdx.x * 256 + threadIdx.x;
    if (idx >= 11 * 16 * 16 * 32) return;
    int kk = idx & 31, m = (idx >> 5) & 15, ot = (idx >> 9) & 15, kc = idx >> 13;
    int oc = ot * 16 + m, k = kc * 32 + kk;
    float v = (k < C0) ? w[oc * C0 + k] : 0.f;
    wf[idx] = f2bf(v);
}

// conv weights [OC][IC][3][3] -> tiled [IC/32][9 tap][OC/16][16][32] bf16
__global__ __launch_bounds__(256) void prep_wt3x3_kernel(
    const float* __restrict__ w, u16* __restrict__ wf, int OC, int IC)
{
    int idx = blockIdx.x * 256 + threadIdx.x;
    if (idx >= OC * IC * 9) return;
    int OCT = OC >> 4;
    int kk = idx & 31; int rest = idx >> 5;
    int m  = rest & 15; rest >>= 4;
    int ot = rest % OCT; rest /= OCT;
    int tap = rest % 9; int kc = rest / 9;
    int oc = ot * 16 + m, k = kc * 32 + kk;
    wf[idx] = f2bf(w[(oc * IC + k) * 9 + tap]);
}

// head weights [256][132*49] -> wtHt[oc][6272] bf16 with k' = s*128 + c
__global__ __launch_bounds__(256) void prep_wtH_kernel(
    const float* __restrict__ hw, u16* __restrict__ wtHt)
{
    int idx = blockIdx.x * 256 + threadIdx.x;
    if (idx >= 256 * KRF) return;
    int oc = idx / KRF, r = idx % KRF;
    int s = r >> 7, c = r & 127;
    wtHt[idx] = f2bf(hw[oc * KHEAD + c * 49 + s]);
}

// fc weights [256][256] fp32 -> bf16 straight copy (already [oc][k])
__global__ __launch_bounds__(256) void cvt_fc_kernel(
    const float* __restrict__ w, u16* __restrict__ wf)
{
    int idx = blockIdx.x * 256 + threadIdx.x;
    if (idx < 256 * 256) wf[idx] = f2bf(w[idx]);
}

// wsum4[oc][j] = sum over 7x7 of head_w[oc][128+j][.][.]
__global__ __launch_bounds__(256) void wsum_kernel(
    const float* __restrict__ hw, float* __restrict__ wsum4)
{
    int idx = blockIdx.x * 256 + threadIdx.x;
    if (idx >= 256 * 4) return;
    int oc = idx >> 2, j = idx & 3;
    const float* p = hw + (long long)oc * KHEAD + (128 + j) * 49;
    float s = 0.f;
    #pragma unroll
    for (int t = 0; t < 49; ++t) s += p[t];
    wsum4[idx] = s;
}

// ---------------------------------------------------------------------------
// conv1 (1x1, K=324 padded to 352): corr [4][324][9216] fp32 ->
// act1p [4][98][98][256] bf16 (interior), MFMA.
// Block: 128 oc x 128 pix; wave 64oc x 64pix; grid (72, 2, 4).
__global__ __launch_bounds__(256) void conv1_mfma(
    const float* __restrict__ corr, const u16* __restrict__ wf,
    const float* __restrict__ bias, u16* __restrict__ outp)
{
    __shared__ __align__(16) u16 Bs[128 * 40];
    const int tid = threadIdx.x;
    const int b = blockIdx.z;
    const int p0 = blockIdx.x * 128;
    const int lane = tid & 63, wid = tid >> 6;
    const int q = lane >> 4, m16 = lane & 15;
    const int woc = wid & 1, wpx = wid >> 1;
    const int fragoff = m16 * 4 + q;
    const bf16x8* W8 = (const bf16x8*)wf;

    f32x4 acc[4][4];
    #pragma unroll
    for (int i = 0; i < 4; ++i)
        #pragma unroll
        for (int j = 0; j < 4; ++j) acc[i][j] = (f32x4){0.f,0.f,0.f,0.f};

    const int lb = m16 * 40 + q * 8;
    for (int kc = 0; kc < 11; ++kc) {
        for (int i = tid; i < 4096; i += 256) {
            int kl = i >> 7, pl = i & 127;
            int k = kc * 32 + kl;
            float v = (k < C0) ? corr[((long long)b * C0 + k) * PIX + p0 + pl] : 0.f;
            Bs[pl * 40 + kl] = f2bf(v);
        }
        __syncthreads();
        bf16x8 a[4], bb[4];
        #pragma unroll
        for (int i = 0; i < 4; ++i) {
            int otg = blockIdx.y * 8 + woc * 4 + i;
            a[i] = W8[(kc * 16 + otg) * 64 + fragoff];
        }
        #pragma unroll
        for (int pt = 0; pt < 4; ++pt)
            bb[pt] = *(const bf16x8*)&Bs[(wpx * 64 + pt * 16) * 40 + lb];
        #pragma unroll
        for (int i = 0; i < 4; ++i)
            #pragma unroll
            for (int pt = 0; pt < 4; ++pt)
                acc[i][pt] = __builtin_amdgcn_mfma_f32_16x16x32_bf16(a[i], bb[pt], acc[i][pt], 0, 0, 0);
        __syncthreads();
    }
    #pragma unroll
    for (int i = 0; i < 4; ++i) {
        int oc4 = blockIdx.y * 128 + woc * 64 + i * 16 + q * 4;
        f32x4 bv = *(const f32x4*)(bias + oc4);
        #pragma unroll
        for (int pt = 0; pt < 4; ++pt) {
            int p = p0 + wpx * 64 + pt * 16 + m16;
            int y = p / 96, x = p % 96;
            f32x4 d = acc[i][pt];
            u16x4 pk;
            #pragma unroll
            for (int r = 0; r < 4; ++r) pk[r] = f2bf(fmaxf(d[r] + bv[r], 0.f));
            long long dst = (((long long)(b * 98 + y + 1) * 98) + x + 1) * 256 + oc4;
            *(u16x4*)(outp + dst) = pk;
        }
    }
}

// ---------------------------------------------------------------------------
// conv3x3 MFMA implicit GEMM. Input padded channel-last [4][98][98][256] bf16.
// Block: 128 oc x (4 rows x 32 cols). Wave: 64 oc x (2 rows x 32 cols).
template<int COUT, bool PADOUT>
__global__ __launch_bounds__(256) void conv3x3_mfma(
    const u16* __restrict__ inp, const u16* __restrict__ wf,
    const float* __restrict__ bias, u16* __restrict__ outp)
{
    __shared__ __align__(16) u16 Bs[204 * 40];   // 6 rows x 34 cols halo, 32k (pad 40)
    const int OCT = COUT / 16;
    const int tid = threadIdx.x;
    const int b = blockIdx.z;
    const int tcol = blockIdx.x % 3, trow = blockIdx.x / 3;
    const int x0 = tcol * 32, y0 = trow * 4;
    const int lane = tid & 63, wid = tid >> 6;
    const int q = lane >> 4, m16 = lane & 15;
    const int woc = wid & 1, wpx = wid >> 1;
    const int fragoff = m16 * 4 + q;
    const bf16x8* W8 = (const bf16x8*)wf;

    f32x4 acc[4][4];
    #pragma unroll
    for (int i = 0; i < 4; ++i)
        #pragma unroll
        for (int j = 0; j < 4; ++j) acc[i][j] = (f32x4){0.f,0.f,0.f,0.f};

    const int lb = m16 * 40 + q * 8;
    for (int kc = 0; kc < 8; ++kc) {
        for (int i = tid; i < 816; i += 256) {
            int p = i >> 2, qd = i & 3;
            int rowh = p / 34, colh = p % 34;
            const u16* src = inp + ((((long long)(b * 98 + y0 + rowh)) * 98 + x0 + colh) * 256
                                    + kc * 32 + qd * 8);
            *(bf16x8*)&Bs[p * 40 + qd * 8] = *(const bf16x8*)src;
        }
        __syncthreads();
        #pragma unroll
        for (int tap = 0; tap < 9; ++tap) {
            const int dy = tap / 3, dx = tap % 3;
            bf16x8 a[4], bb[4];
            #pragma unroll
            for (int i = 0; i < 4; ++i) {
                int otg = blockIdx.y * 8 + woc * 4 + i;
                a[i] = W8[(size_t)((kc * 9 + tap) * OCT + otg) * 64 + fragoff];
            }
            #pragma unroll
            for (int r = 0; r < 2; ++r)
                #pragma unroll
                for (int ct = 0; ct < 2; ++ct)
                    bb[r * 2 + ct] = *(const bf16x8*)&Bs[((wpx * 2 + r + dy) * 34 + ct * 16 + dx) * 40 + lb];
            #pragma unroll
            for (int i = 0; i < 4; ++i)
                #pragma unroll
                for (int j = 0; j < 4; ++j)
                    acc[i][j] = __builtin_amdgcn_mfma_f32_16x16x32_bf16(a[i], bb[j], acc[i][j], 0, 0, 0);
        }
        __syncthreads();
    }
    #pragma unroll
    for (int i = 0; i < 4; ++i) {
        int oc4 = blockIdx.y * 128 + woc * 64 + i * 16 + q * 4;
        f32x4 bv = *(const f32x4*)(bias + oc4);
        #pragma unroll
        for (int r = 0; r < 2; ++r) {
            int y = y0 + wpx * 2 + r;
            #pragma unroll
            for (int ct = 0; ct < 2; ++ct) {
                int x = x0 + ct * 16 + m16;
                f32x4 d = acc[i][r * 2 + ct];
                u16x4 pk;
                #pragma unroll
                for (int rg = 0; rg < 4; ++rg) pk[rg] = f2bf(fmaxf(d[rg] + bv[rg], 0.f));
                long long dst;
                if (PADOUT) dst = (((long long)(b * 98 + y + 1) * 98) + x + 1) * COUT + oc4;
                else        dst = (((long long)(b * 96 + y) * 96) + x) * COUT + oc4;
                *(u16x4*)(outp + dst) = pk;
            }
        }
    }
}

// ---------------------------------------------------------------------------
// ROI align: rel [4][96][96][128] bf16 -> rf [192][49*128] bf16 (k' = s*128+c)
__global__ __launch_bounds__(256) void roi_align_cl(
    const u16* __restrict__ rel, const float* __restrict__ det1,
    u16* __restrict__ rf)
{
    const int roi = blockIdx.x, tid = threadIdx.x;
    const int c = tid & 127, sb = tid >> 7;
    const int b = roi / MM, m = roi % MM;
    const float* d = det1 + (long long)(b * MM + m) * 10;
    float cx = d[2], cy = d[3], w = d[4], h = d[5];
    float x1f = cx - w * 0.5f, y1f = cy - h * 0.5f;
    float x1 = x1f * 0.125f, y1 = y1f * 0.125f;
    float x2 = (x1f + w) * 0.125f, y2 = (y1f + h) * 0.125f;
    float bh = (y2 - y1) * (1.f / 7.f), bw = (x2 - x1) * (1.f / 7.f);
    const u16* fb = rel + (long long)b * PIX * 128 + c;
    for (int s = sb; s < 49; s += 2) {
        int i = s / 7, j = s % 7;
        float sum = 0.f;
        #pragma unroll
        for (int di = 0; di < 2; ++di) {
            float y = y1 + ((float)(2 * i + di) + 0.5f) * 0.5f * bh;
            y = fminf(fmaxf(y, 0.f), 95.f);
            int yy0 = (int)floorf(y);
            int yy1 = min(yy0 + 1, 95);
            float wy = y - (float)yy0;
            #pragma unroll
            for (int dj = 0; dj < 2; ++dj) {
                float x = x1 + ((float)(2 * j + dj) + 0.5f) * 0.5f * bw;
                x = fminf(fmaxf(x, 0.f), 95.f);
                int xx0 = (int)floorf(x);
                int xx1 = min(xx0 + 1, 95);
                float wx = x - (float)xx0;
                float f00 = b2f(fb[((long long)yy0 * 96 + xx0) * 128]);
                float f01 = b2f(fb[((long long)yy0 * 96 + xx1) * 128]);
                float f10 = b2f(fb[((long long)yy1 * 96 + xx0) * 128]);
                float f11 = b2f(fb[((long long)yy1 * 96 + xx1) * 128]);
                sum += f00 * (1.f - wy) * (1.f - wx) + f01 * (1.f - wy) * wx
                     + f10 * wy * (1.f - wx) + f11 * wy * wx;
            }
        }
        rf[(long long)roi * KRF + s * 128 + c] = f2bf(sum * 0.25f);
    }
}

// ---------------------------------------------------------------------------
// Head GEMM split-K: Gpart[split][roi][oc] = sum_{k in split} rf[roi][k]*wtHt[oc][k]
// Block 64 rois x 128 oc; grid (6, 14).
__global__ __launch_bounds__(256) void head_gemm_mfma(
    const u16* __restrict__ rf, const u16* __restrict__ wtHt,
    float* __restrict__ Gpart)
{
    __shared__ __align__(16) u16 As[64 * 40];
    __shared__ __align__(16) u16 Bs[128 * 40];
    const int tid = threadIdx.x;
    const int rb = blockIdx.x >> 1, ob = blockIdx.x & 1;
    const int split = blockIdx.y;
    const int lane = tid & 63, wid = tid >> 6;
    const int q = lane >> 4, m16 = lane & 15;
    const int wr = wid & 1, wo = wid >> 1;

    f32x4 acc[2][4];
    #pragma unroll
    for (int i = 0; i < 2; ++i)
        #pragma unroll
        for (int j = 0; j < 4; ++j) acc[i][j] = (f32x4){0.f,0.f,0.f,0.f};

    for (int cch = 0; cch < CPS; ++cch) {
        int k0 = (split * CPS + cch) * 32;
        {
            int rl = tid >> 2, qd = tid & 3;
            *(bf16x8*)&As[rl * 40 + qd * 8] =
                *(const bf16x8*)&rf[(long long)(rb * 64 + rl) * KRF + k0 + qd * 8];
        }
        for (int i = tid; i < 512; i += 256) {
            int ol = i >> 2, qd = i & 3;
            *(bf16x8*)&Bs[ol * 40 + qd * 8] =
                *(const bf16x8*)&wtHt[(long long)(ob * 128 + ol) * KRF + k0 + qd * 8];
        }
        __syncthreads();
        bf16x8 a[2], bb[4];
        #pragma unroll
        for (int rt = 0; rt < 2; ++rt)
            a[rt] = *(const bf16x8*)&As[(wr * 32 + rt * 16 + m16) * 40 + q * 8];
        #pragma unroll
        for (int ot = 0; ot < 4; ++ot)
            bb[ot] = *(const bf16x8*)&Bs[(wo * 64 + ot * 16 + m16) * 40 + q * 8];
        #pragma unroll
        for (int rt = 0; rt < 2; ++rt)
            #pragma unroll
            for (int ot = 0; ot < 4; ++ot)
                acc[rt][ot] = __builtin_amdgcn_mfma_f32_16x16x32_bf16(a[rt], bb[ot], acc[rt][ot], 0, 0, 0);
        __syncthreads();
    }
    #pragma unroll
    for (int rt = 0; rt < 2; ++rt)
        #pragma unroll
        for (int ot = 0; ot < 4; ++ot) {
            int oc = ob * 128 + wo * 64 + ot * 16 + m16;
            #pragma unroll
            for (int rg = 0; rg < 4; ++rg) {
                int roi = rb * 64 + wr * 32 + rt * 16 + q * 4 + rg;
                Gpart[((long long)split * NROI + roi) * 256 + oc] = acc[rt][ot][rg];
            }
        }
}

__global__ __launch_bounds__(256) void reduce_G_kernel(
    const float* __restrict__ Gpart, float* __restrict__ G)
{
    int idx = blockIdx.x * 256 + threadIdx.x;
    if (idx >= NROI * 256) return;
    float s = 0.f;
    #pragma unroll
    for (int sp = 0; sp < SPLITS; ++sp) s += Gpart[(long long)sp * NROI * 256 + idx];
    G[idx] = s;
}

// ---------------------------------------------------------------------------
// Per-pair geometry
__global__ __launch_bounds__(256) void pair_kernel(
    const float* __restrict__ d1, const float* __restrict__ d2,
    float* __restrict__ pos4, float* __restrict__ labels,
    float* __restrict__ valid)
{
    int pair = blockIdx.x * 256 + threadIdx.x;
    if (pair >= NPAIR) return;
    int b = pair / (MM * MM); int rem = pair % (MM * MM);
    int m1 = rem / MM, m2 = rem % MM;
    const float* r1 = d1 + (long long)(b * MM + m1) * 10;
    const float* r2 = d2 + (long long)(b * MM + m2) * 10;
    float v1 = r1[0], id1 = r1[1], cxa = r1[2], cya = r1[3], wa = r1[4], ha = r1[5];
    float v2 = r2[0], id2 = r2[1], cxb = r2[2], cyb = r2[3], wb = r2[4], hb = r2[5];
    const float eps = 1e-6f;
    float ax1 = cxa - wa * 0.5f, ay1 = cya - ha * 0.5f;
    float ax2 = ax1 + wa,        ay2 = ay1 + ha;
    float bx1 = cxb - wb * 0.5f, by1 = cyb - hb * 0.5f;
    float bx2 = bx1 + wb,        by2 = by1 + hb;
    float ccx1 = (ax1 + ax2) * 0.5f, ccy1 = (ay1 + ay2) * 0.5f;
    float ww1 = fmaxf(ax2 - ax1, eps), hh1 = fmaxf(ay2 - ay1, eps);
    float ccx2 = (bx1 + bx2) * 0.5f, ccy2 = (by1 + by2) * 0.5f;
    float ww2 = fmaxf(bx2 - bx1, eps), hh2 = fmaxf(by2 - by1, eps);
    pos4[pair * 4 + 0] = (ccx2 - ccx1) / ww1;
    pos4[pair * 4 + 1] = (ccy2 - ccy1) / hh1;
    pos4[pair * 4 + 2] = logf(ww2 / ww1);
    pos4[pair * 4 + 3] = logf(hh2 / hh1);
    labels[pair] = (id1 == id2) ? 1.f : 0.f;
    valid[pair]  = (v1 != -1.f && v2 != -1.f) ? 1.f : 0.f;
}

// X[pair][oc] = G[roi][oc] + hb[oc] + pos4 . wsum4  (bf16 out)
__global__ __launch_bounds__(256) void build_X_kernel(
    const float* __restrict__ G, const float* __restrict__ pos4,
    const float* __restrict__ wsum4, const float* __restrict__ hb,
    u16* __restrict__ X)
{
    int idx = blockIdx.x * 256 + threadIdx.x;   // 9216*256 exactly
    int oc = idx & 255;
    int pair = idx >> 8;
    int roi = pair / MM;
    const float* p4 = pos4 + pair * 4;
    const float* w4 = wsum4 + oc * 4;
    float v = G[roi * 256 + oc] + hb[oc]
            + p4[0] * w4[0] + p4[1] * w4[1] + p4[2] * w4[2] + p4[3] * w4[3];
    X[idx] = f2bf(v);
}

// ---------------------------------------------------------------------------
// FC GEMM: out[pair][oc] = act( sum_k in[pair][k]*w[oc][k] + bias[oc] )
// in [9216][256] bf16, w [256][256] bf16. Block 128 oc x 128 pairs.
__global__ __launch_bounds__(256) void fc_mfma(
    const u16* __restrict__ inA, const u16* __restrict__ wgt,
    const float* __restrict__ bias, u16* __restrict__ outp, int relu)
{
    __shared__ __align__(16) u16 As[128 * 40];
    __shared__ __align__(16) u16 Bs[128 * 40];
    const int tid = threadIdx.x;
    const int p0 = blockIdx.x * 128, ocb = blockIdx.y * 128;
    const int lane = tid & 63, wid = tid >> 6;
    const int q = lane >> 4, m16 = lane & 15;
    const int woc = wid & 1, wpx = wid >> 1;

    f32x4 acc[4][4];
    #pragma unroll
    for (int i = 0; i < 4; ++i)
        #pragma unroll
        for (int j = 0; j < 4; ++j) acc[i][j] = (f32x4){0.f,0.f,0.f,0.f};

    for (int kc = 0; kc < 8; ++kc) {
        int k0 = kc * 32;
        for (int i = tid; i < 512; i += 256) {
            int ol = i >> 2, qd = i & 3;
            *(bf16x8*)&As[ol * 40 + qd * 8] =
                *(const bf16x8*)&wgt[(ocb + ol) * 256 + k0 + qd * 8];
            *(bf16x8*)&Bs[ol * 40 + qd * 8] =
                *(const bf16x8*)&inA[(long long)(p0 + ol) * 256 + k0 + qd * 8];
        }
        __syncthreads();
        bf16x8 a[4], bb[4];
        #pragma unroll
        for (int i = 0; i < 4; ++i)
            a[i] = *(const bf16x8*)&As[(woc * 64 + i * 16 + m16) * 40 + q * 8];
        #pragma unroll
        for (int pt = 0; pt < 4; ++pt)
            bb[pt] = *(const bf16x8*)&Bs[(wpx * 64 + pt * 16 + m16) * 40 + q * 8];
        #pragma unroll
        for (int i = 0; i < 4; ++i)
            #pragma unroll
            for (int pt = 0; pt < 4; ++pt)
                acc[i][pt] = __builtin_amdgcn_mfma_f32_16x16x32_bf16(a[i], bb[pt], acc[i][pt], 0, 0, 0);
        __syncthreads();
    }
    #pragma unroll
    for (int i = 0; i < 4; ++i) {
        int oc4 = ocb + woc * 64 + i * 16 + q * 4;
        f32x4 bv = *(const f32x4*)(bias + oc4);
        #pragma unroll
        for (int pt = 0; pt < 4; ++pt) {
            int pair = p0 + wpx * 64 + pt * 16 + m16;
            f32x4 d = acc[i][pt];
            u16x4 pk;
            #pragma unroll
            for (int rg = 0; rg < 4; ++rg) {
                float v = d[rg] + bv[rg];
                if (relu) v = fmaxf(v, 0.f);
                pk[rg] = f2bf(v);
            }
            *(u16x4*)(outp + (long long)pair * 256 + oc4) = pk;
        }
    }
}

// ---------------------------------------------------------------------------
// scores[pair] = sum_k cls_w[k]*H2[pair][k] + cls_b   (H2 [9216][256] bf16)
__global__ __launch_bounds__(256) void cls_kernel(
    const u16* __restrict__ H2, const float* __restrict__ cw,
    const float* __restrict__ cb, float* __restrict__ scores)
{
    __shared__ float wsm[256];
    int tid = threadIdx.x;
    wsm[tid] = cw[tid];
    __syncthreads();
    int pr = tid >> 2, qq = tid & 3;
    int pair = blockIdx.x * 64 + pr;
    const bf16x8* hp = (const bf16x8*)(H2 + (long long)pair * 256);
    float acc = 0.f;
    #pragma unroll
    for (int k8 = 0; k8 < 8; ++k8) {
        bf16x8 hv = hp[qq * 8 + k8];
        #pragma unroll
        for (int e = 0; e < 8; ++e)
            acc += b2f((u16)hv[e]) * wsm[qq * 64 + k8 * 8 + e];
    }
    acc += __shfl_xor(acc, 1, 64);
    acc += __shfl_xor(acc, 2, 64);
    if (qq == 0) scores[pair] = acc + cb[0];
}

// ---------------------------------------------------------------------------
extern "C" void kernel_launch(void* const* d_in, const int* in_sizes, int n_in,
                              void* d_out, int out_size, void* d_ws, size_t ws_size,
                              hipStream_t stream) {
    const float* corr   = (const float*)d_in[0];
    const float* det1   = (const float*)d_in[2];
    const float* det2   = (const float*)d_in[3];
    const float* c1w    = (const float*)d_in[4];
    const float* c1b    = (const float*)d_in[5];
    const float* c2w    = (const float*)d_in[6];
    const float* c2b    = (const float*)d_in[7];
    const float* c3w    = (const float*)d_in[8];
    const float* c3b    = (const float*)d_in[9];
    const float* hw     = (const float*)d_in[10];
    const float* hbias  = (const float*)d_in[11];
    const float* f6w    = (const float*)d_in[12];
    const float* f6b    = (const float*)d_in[13];
    const float* f7w    = (const float*)d_in[14];
    const float* f7b    = (const float*)d_in[15];
    const float* clsw   = (const float*)d_in[16];
    const float* clsb   = (const float*)d_in[17];
    float* out = (float*)d_out;

    char* base = (char*)d_ws;
    auto alloc = [&](size_t bytes) { char* p = base; base += (bytes + 255) & ~(size_t)255; return p; };

    const size_t ACTP_BYTES = (size_t)NB * 98 * 98 * 256 * 2;   // 19,668,992
    u16*   act1p = (u16*)  alloc(ACTP_BYTES);
    u16*   act2p = (u16*)  alloc(ACTP_BYTES);
    u16*   rel   = (u16*)  alloc((size_t)NB * PIX * 128 * 2);
    u16*   wt1f  = (u16*)  alloc(11 * 16 * 512 * 2);
    u16*   wt2f  = (u16*)  alloc((size_t)8 * 9 * 16 * 512 * 2);
    u16*   wt3f  = (u16*)  alloc((size_t)8 * 9 * 8 * 512 * 2);
    u16*   wtHt  = (u16*)  alloc((size_t)256 * KRF * 2);
    u16*   w6c   = (u16*)  alloc(256 * 256 * 2);
    u16*   w7c   = (u16*)  alloc(256 * 256 * 2);
    float* wsum4 = (float*)alloc(256 * 4 * 4);
    u16*   rf    = (u16*)  alloc((size_t)NROI * KRF * 2);
    float* Gpart = (float*)alloc((size_t)SPLITS * NROI * 256 * 4);
    float* G     = (float*)alloc(NROI * 256 * 4);
    float* pos4  = (float*)alloc(NPAIR * 4 * 4);
    u16*   X     = (u16*)  alloc((size_t)NPAIR * 256 * 2);
    u16*   H1    = (u16*)  alloc((size_t)NPAIR * 256 * 2);
    u16*   H2    = (u16*)  alloc((size_t)NPAIR * 256 * 2);

    float* scores_out = out;
    float* labels_out = out + NPAIR;
    float* valid_out  = out + 2 * NPAIR;

    // 0. zero padded activation buffers (act1p+act2p contiguous modulo 256-pad; zero each)
    {
        long long n16 = (long long)ACTP_BYTES / 16;
        int blocks = (int)((n16 + 255) / 256);
        zero16_kernel<<<blocks, 256, 0, stream>>>((i32x4*)act1p, n16);
        zero16_kernel<<<blocks, 256, 0, stream>>>((i32x4*)act2p, n16);
    }

    // 1. weight prep
    prep_wt1_kernel<<<(11 * 16 * 512 + 255) / 256, 256, 0, stream>>>(c1w, wt1f);
    prep_wt3x3_kernel<<<(256 * 256 * 9 + 255) / 256, 256, 0, stream>>>(c2w, wt2f, 256, 256);
    prep_wt3x3_kernel<<<(128 * 256 * 9 + 255) / 256, 256, 0, stream>>>(c3w, wt3f, 128, 256);
    prep_wtH_kernel<<<(256 * KRF + 255) / 256, 256, 0, stream>>>(hw, wtHt);
    cvt_fc_kernel<<<256, 256, 0, stream>>>(f6w, w6c);
    cvt_fc_kernel<<<256, 256, 0, stream>>>(f7w, w7c);
    wsum_kernel<<<4, 256, 0, stream>>>(hw, wsum4);

    // 2. conv1 (1x1 GEMM, K=324)
    conv1_mfma<<<dim3(72, 2, NB), 256, 0, stream>>>(corr, wt1f, c1b, act1p);

    // 3. conv2 (3x3, 256->256), padded out
    conv3x3_mfma<256, true><<<dim3(72, 2, NB), 256, 0, stream>>>(act1p, wt2f, c2b, act2p);

    // 4. conv3 (3x3, 256->128), flat channel-last out
    conv3x3_mfma<128, false><<<dim3(72, 1, NB), 256, 0, stream>>>(act2p, wt3f, c3b, rel);

    // 5. ROI align
    roi_align_cl<<<NROI, 256, 0, stream>>>(rel, det1, rf);

    // 6. head GEMM split-K + reduce
    head_gemm_mfma<<<dim3(6, SPLITS), 256, 0, stream>>>(rf, wtHt, Gpart);
    reduce_G_kernel<<<(NROI * 256 + 255) / 256, 256, 0, stream>>>(Gpart, G);

    // 7. pair geometry (labels/valid straight to output)
    pair_kernel<<<NPAIR / 256, 256, 0, stream>>>(det1, det2, pos4, labels_out, valid_out);

    // 8. assemble X [pair][256] bf16
    build_X_kernel<<<NPAIR * 256 / 256, 256, 0, stream>>>(G, pos4, wsum4, hbias, X);

    // 9. fc6, fc7
    fc_mfma<<<dim3(72, 2), 256, 0, stream>>>(X, w6c, f6b, H1, 1);
    fc_mfma<<<dim3(72, 2), 256, 0, stream>>>(H1, w7c, f7b, H2, 1);

    // 10. classifier
    cls_kernel<<<NPAIR / 64, 256, 0, stream>>>(H2, clsw, clsb, scores_out);
}

// Round 3
// 346.820 us; speedup vs baseline: 5.3969x; 1.1760x over previous
//
#include <hip/hip_runtime.h>
#include <hip/hip_bf16.h>

#define NB    4
#define HH    96
#define WW    96
#define PIX   9216
#define C0    324
#define MM    48
#define NROI  192
#define NPAIR 9216
#define KHEAD 6468
#define KRF   6272
#define SPLITS 28
#define CPS    7     // 28*7*32 = 6272

typedef unsigned short u16;
typedef __attribute__((ext_vector_type(8))) short bf16x8;
typedef __attribute__((ext_vector_type(4))) float f32x4;
typedef __attribute__((ext_vector_type(4))) unsigned short u16x4;
typedef __attribute__((ext_vector_type(4))) int i32x4;

__device__ __forceinline__ u16 f2bf(float f) {
    __hip_bfloat16 h = __float2bfloat16(f);
    union { __hip_bfloat16 h; u16 u; } c; c.h = h; return c.u;
}
__device__ __forceinline__ float b2f(u16 u) {
    union { unsigned int i; float f; } c; c.i = ((unsigned int)u) << 16; return c.f;
}

// ---------------------------------------------------------------------------
// Zero only the halo ring of act1p/act2p: 388 halo px * 256 ch * 4 img * 2 bufs
__global__ __launch_bounds__(256) void zero_halo(u16* __restrict__ a1, u16* __restrict__ a2)
{
    int idx = blockIdx.x * 256 + threadIdx.x;   // 99328 total
    int c8 = idx & 31;
    int t = idx >> 5;
    int h = t % 388, img = t / 388;             // img 0..7
    u16* base = (img & 4) ? a2 : a1;
    int b = img & 3;
    int y, x;
    if (h < 98)       { y = 0;  x = h; }
    else if (h < 196) { y = 97; x = h - 98; }
    else { int r = (h - 196) >> 1; x = ((h - 196) & 1) * 97; y = 1 + r; }
    long long off = (((long long)(b * 98 + y)) * 98 + x) * 256 + c8 * 8;
    i32x4 z = {0, 0, 0, 0};
    *(i32x4*)(base + off) = z;
}

// ---------------------------------------------------------------------------
// One merged prep dispatch. Block ranges:
// [0,352) wt1 | [352,2656) wt2 | [2656,3808) wt3 | [3808,10080) wtH
// [10080,10336) w6 | [10336,10592) w7 | [10592,10596) wsum
__global__ __launch_bounds__(256) void prep_all(
    const float* __restrict__ c1w, const float* __restrict__ c2w,
    const float* __restrict__ c3w, const float* __restrict__ hw,
    const float* __restrict__ f6w, const float* __restrict__ f7w,
    u16* __restrict__ wt1f, u16* __restrict__ wt2f, u16* __restrict__ wt3f,
    u16* __restrict__ wtHt, u16* __restrict__ w6c, u16* __restrict__ w7c,
    float* __restrict__ wsum4)
{
    int blk = blockIdx.x, tid = threadIdx.x;
    if (blk < 352) {
        int idx = blk * 256 + tid;            // 11*16*16*32 = 90112
        if (idx >= 90112) return;
        int kk = idx & 31, m = (idx >> 5) & 15, ot = (idx >> 9) & 15, kc = idx >> 13;
        int oc = ot * 16 + m, k = kc * 32 + kk;
        wt1f[idx] = f2bf((k < C0) ? c1w[oc * C0 + k] : 0.f);
    } else if (blk < 2656) {
        int idx = (blk - 352) * 256 + tid;    // 256*256*9
        int kk = idx & 31; int rest = idx >> 5;
        int m = rest & 15; rest >>= 4;
        int ot = rest & 15; rest >>= 4;
        int tap = rest % 9; int kc = rest / 9;
        wt2f[idx] = f2bf(c2w[((ot * 16 + m) * 256 + kc * 32 + kk) * 9 + tap]);
    } else if (blk < 3808) {
        int idx = (blk - 2656) * 256 + tid;   // 128*256*9
        int kk = idx & 31; int rest = idx >> 5;
        int m = rest & 15; rest >>= 4;
        int ot = rest & 7; rest >>= 3;
        int tap = rest % 9; int kc = rest / 9;
        wt3f[idx] = f2bf(c3w[((ot * 16 + m) * 256 + kc * 32 + kk) * 9 + tap]);
    } else if (blk < 10080) {
        int idx = (blk - 3808) * 256 + tid;   // 256*6272
        int oc = idx / KRF, r = idx % KRF;
        int s = r >> 7, c = r & 127;
        wtHt[idx] = f2bf(hw[oc * KHEAD + c * 49 + s]);
    } else if (blk < 10336) {
        int idx = (blk - 10080) * 256 + tid;
        w6c[idx] = f2bf(f6w[idx]);
    } else if (blk < 10592) {
        int idx = (blk - 10336) * 256 + tid;
        w7c[idx] = f2bf(f7w[idx]);
    } else {
        int idx = (blk - 10592) * 256 + tid;  // 1024
        if (idx >= 1024) return;
        int oc = idx >> 2, j = idx & 3;
        const float* p = hw + (long long)oc * KHEAD + (128 + j) * 49;
        float s = 0.f;
        #pragma unroll
        for (int t = 0; t < 49; ++t) s += p[t];
        wsum4[idx] = s;
    }
}

// ---------------------------------------------------------------------------
// corr [4][324][9216] f32 -> corrT [4][9216][352] bf16 (k in [324,352) zero)
// Block: 64 px x 352 k, LDS transpose. Grid (144, 4).
__global__ __launch_bounds__(256) void cvt_corr(
    const float* __restrict__ corr, u16* __restrict__ corrT)
{
    __shared__ u16 L[64 * 354];
    const int tid = threadIdx.x;
    const int b = blockIdx.y;
    const int p0 = blockIdx.x * 64;
    const int px4 = (tid & 15) * 4;
    const int kr = tid >> 4;
    #pragma unroll
    for (int s = 0; s < 22; ++s) {
        int k = s * 16 + kr;
        float4 v = {0.f, 0.f, 0.f, 0.f};
        if (k < C0) v = *(const float4*)&corr[((long long)(b * C0 + k)) * PIX + p0 + px4];
        L[(px4 + 0) * 354 + k] = f2bf(v.x);
        L[(px4 + 1) * 354 + k] = f2bf(v.y);
        L[(px4 + 2) * 354 + k] = f2bf(v.z);
        L[(px4 + 3) * 354 + k] = f2bf(v.w);
    }
    __syncthreads();
    #pragma unroll
    for (int it = 0; it < 44; ++it) {
        int idx = tid + it * 256;           // < 11264 = 64*176
        int px = idx / 176, c4 = idx % 176;
        unsigned int val = *(const unsigned int*)&L[px * 354 + c4 * 2];
        *(unsigned int*)&corrT[((long long)(b * PIX + p0 + px)) * 352 + c4 * 2] = val;
    }
}

// ---------------------------------------------------------------------------
// conv1 (1x1) GEMM: corrT [b][9216][352] bf16, wt1f tiled -> act1p padded.
// Block 64 px x 128 oc, 4 waves (oc-half x px-half). Grid (144, 2, 4).
__global__ __launch_bounds__(256) void conv1_mfma(
    const u16* __restrict__ corrT, const u16* __restrict__ wf,
    const float* __restrict__ bias, u16* __restrict__ outp)
{
    __shared__ __align__(16) u16 Bs[64 * 40];
    const int tid = threadIdx.x;
    const int b = blockIdx.z;
    const int p0 = blockIdx.x * 64;
    const int lane = tid & 63, wid = tid >> 6;
    const int q = lane >> 4, m16 = lane & 15;
    const int woc = wid & 1, wpx = wid >> 1;
    const int fragoff = m16 * 4 + q;
    const bf16x8* W8 = (const bf16x8*)wf;

    const int spx = tid >> 2, sqd = tid & 3;
    const u16* srcbase = corrT + ((long long)(b * PIX + p0 + spx)) * 352 + sqd * 8;

    f32x4 acc[4][2];
    #pragma unroll
    for (int i = 0; i < 4; ++i)
        #pragma unroll
        for (int j = 0; j < 2; ++j) acc[i][j] = (f32x4){0.f, 0.f, 0.f, 0.f};

    bf16x8 stg = *(const bf16x8*)srcbase;
    for (int kc = 0; kc < 11; ++kc) {
        __syncthreads();
        *(bf16x8*)&Bs[spx * 40 + sqd * 8] = stg;
        __syncthreads();
        if (kc < 10) stg = *(const bf16x8*)(srcbase + (kc + 1) * 32);
        bf16x8 a[4], bb[2];
        #pragma unroll
        for (int i = 0; i < 4; ++i)
            a[i] = W8[(kc * 16 + blockIdx.y * 8 + woc * 4 + i) * 64 + fragoff];
        #pragma unroll
        for (int pt = 0; pt < 2; ++pt)
            bb[pt] = *(const bf16x8*)&Bs[(wpx * 32 + pt * 16 + m16) * 40 + q * 8];
        #pragma unroll
        for (int i = 0; i < 4; ++i)
            #pragma unroll
            for (int pt = 0; pt < 2; ++pt)
                acc[i][pt] = __builtin_amdgcn_mfma_f32_16x16x32_bf16(a[i], bb[pt], acc[i][pt], 0, 0, 0);
    }
    #pragma unroll
    for (int i = 0; i < 4; ++i) {
        int oc4 = blockIdx.y * 128 + woc * 64 + i * 16 + q * 4;
        f32x4 bv = *(const f32x4*)(bias + oc4);
        #pragma unroll
        for (int pt = 0; pt < 2; ++pt) {
            int p = p0 + wpx * 32 + pt * 16 + m16;
            int y = p / 96, x = p % 96;
            f32x4 d = acc[i][pt];
            u16x4 pk;
            #pragma unroll
            for (int r = 0; r < 4; ++r) pk[r] = f2bf(fmaxf(d[r] + bv[r], 0.f));
            *(u16x4*)(outp + (((long long)(b * 98 + y + 1) * 98) + x + 1) * 256 + oc4) = pk;
        }
    }
}

// ---------------------------------------------------------------------------
// conv3x3 MFMA implicit GEMM, unrolled staging + reg prefetch.
template<int COUT, bool PADOUT>
__global__ __launch_bounds__(256) void conv3x3_mfma(
    const u16* __restrict__ inp, const u16* __restrict__ wf,
    const float* __restrict__ bias, u16* __restrict__ outp)
{
    __shared__ __align__(16) u16 Bs[204 * 40];
    const int OCT = COUT / 16;
    const int tid = threadIdx.x;
    const int b = blockIdx.z;
    const int tcol = blockIdx.x % 3, trow = blockIdx.x / 3;
    const int x0 = tcol * 32, y0 = trow * 4;
    const int lane = tid & 63, wid = tid >> 6;
    const int q = lane >> 4, m16 = lane & 15;
    const int woc = wid & 1, wpx = wid >> 1;
    const int fragoff = m16 * 4 + q;
    const bf16x8* W8 = (const bf16x8*)wf;

    const bool stager = (tid < 204);
    const int rowh = tid / 34, colh = tid % 34;
    const u16* sbase = inp + ((((long long)(b * 98 + y0 + rowh)) * 98 + x0 + colh) * 256);

    f32x4 acc[4][4];
    #pragma unroll
    for (int i = 0; i < 4; ++i)
        #pragma unroll
        for (int j = 0; j < 4; ++j) acc[i][j] = (f32x4){0.f, 0.f, 0.f, 0.f};

    bf16x8 r0, r1, r2, r3;
    if (stager) {
        r0 = *(const bf16x8*)(sbase + 0);
        r1 = *(const bf16x8*)(sbase + 8);
        r2 = *(const bf16x8*)(sbase + 16);
        r3 = *(const bf16x8*)(sbase + 24);
    }
    for (int kc = 0; kc < 8; ++kc) {
        __syncthreads();
        if (stager) {
            *(bf16x8*)&Bs[tid * 40 + 0]  = r0;
            *(bf16x8*)&Bs[tid * 40 + 8]  = r1;
            *(bf16x8*)&Bs[tid * 40 + 16] = r2;
            *(bf16x8*)&Bs[tid * 40 + 24] = r3;
        }
        __syncthreads();
        if (kc < 7 && stager) {
            const u16* s = sbase + (kc + 1) * 32;
            r0 = *(const bf16x8*)(s + 0);
            r1 = *(const bf16x8*)(s + 8);
            r2 = *(const bf16x8*)(s + 16);
            r3 = *(const bf16x8*)(s + 24);
        }
        #pragma unroll
        for (int tap = 0; tap < 9; ++tap) {
            const int dy = tap / 3, dx = tap % 3;
            bf16x8 a[4], bb[4];
            #pragma unroll
            for (int i = 0; i < 4; ++i) {
                int otg = blockIdx.y * 8 + woc * 4 + i;
                a[i] = W8[(size_t)((kc * 9 + tap) * OCT + otg) * 64 + fragoff];
            }
            #pragma unroll
            for (int r = 0; r < 2; ++r)
                #pragma unroll
                for (int ct = 0; ct < 2; ++ct)
                    bb[r * 2 + ct] = *(const bf16x8*)&Bs[((wpx * 2 + r + dy) * 34 + ct * 16 + dx) * 40 + m16 * 40 + q * 8];
            #pragma unroll
            for (int i = 0; i < 4; ++i)
                #pragma unroll
                for (int j = 0; j < 4; ++j)
                    acc[i][j] = __builtin_amdgcn_mfma_f32_16x16x32_bf16(a[i], bb[j], acc[i][j], 0, 0, 0);
        }
    }
    #pragma unroll
    for (int i = 0; i < 4; ++i) {
        int oc4 = blockIdx.y * 128 + woc * 64 + i * 16 + q * 4;
        f32x4 bv = *(const f32x4*)(bias + oc4);
        #pragma unroll
        for (int r = 0; r < 2; ++r) {
            int y = y0 + wpx * 2 + r;
            #pragma unroll
            for (int ct = 0; ct < 2; ++ct) {
                int x = x0 + ct * 16 + m16;
                f32x4 d = acc[i][r * 2 + ct];
                u16x4 pk;
                #pragma unroll
                for (int rg = 0; rg < 4; ++rg) pk[rg] = f2bf(fmaxf(d[rg] + bv[rg], 0.f));
                long long dst;
                if (PADOUT) dst = (((long long)(b * 98 + y + 1) * 98) + x + 1) * COUT + oc4;
                else        dst = (((long long)(b * 96 + y) * 96) + x) * COUT + oc4;
                *(u16x4*)(outp + dst) = pk;
            }
        }
    }
}

// ---------------------------------------------------------------------------
// ROI align: rel [4][96][96][128] bf16 -> rf [192][6272] bf16 (k' = s*128+c)
__global__ __launch_bounds__(256) void roi_align_cl(
    const u16* __restrict__ rel, const float* __restrict__ det1,
    u16* __restrict__ rf)
{
    const int roi = blockIdx.x, tid = threadIdx.x;
    const int c = tid & 127, sb = tid >> 7;
    const int b = roi / MM, m = roi % MM;
    const float* d = det1 + (long long)(b * MM + m) * 10;
    float cx = d[2], cy = d[3], w = d[4], h = d[5];
    float x1f = cx - w * 0.5f, y1f = cy - h * 0.5f;
    float x1 = x1f * 0.125f, y1 = y1f * 0.125f;
    float x2 = (x1f + w) * 0.125f, y2 = (y1f + h) * 0.125f;
    float bh = (y2 - y1) * (1.f / 7.f), bw = (x2 - x1) * (1.f / 7.f);
    const u16* fb = rel + (long long)b * PIX * 128 + c;
    for (int s = sb; s < 49; s += 2) {
        int i = s / 7, j = s % 7;
        float sum = 0.f;
        #pragma unroll
        for (int di = 0; di < 2; ++di) {
            float y = y1 + ((float)(2 * i + di) + 0.5f) * 0.5f * bh;
            y = fminf(fmaxf(y, 0.f), 95.f);
            int yy0 = (int)floorf(y);
            int yy1 = min(yy0 + 1, 95);
            float wy = y - (float)yy0;
            #pragma unroll
            for (int dj = 0; dj < 2; ++dj) {
                float x = x1 + ((float)(2 * j + dj) + 0.5f) * 0.5f * bw;
                x = fminf(fmaxf(x, 0.f), 95.f);
                int xx0 = (int)floorf(x);
                int xx1 = min(xx0 + 1, 95);
                float wx = x - (float)xx0;
                float f00 = b2f(fb[((long long)yy0 * 96 + xx0) * 128]);
                float f01 = b2f(fb[((long long)yy0 * 96 + xx1) * 128]);
                float f10 = b2f(fb[((long long)yy1 * 96 + xx0) * 128]);
                float f11 = b2f(fb[((long long)yy1 * 96 + xx1) * 128]);
                sum += f00 * (1.f - wy) * (1.f - wx) + f01 * (1.f - wy) * wx
                     + f10 * wy * (1.f - wx) + f11 * wy * wx;
            }
        }
        rf[(long long)roi * KRF + s * 128 + c] = f2bf(sum * 0.25f);
    }
}

// ---------------------------------------------------------------------------
// Head GEMM split-K (28 splits x 7 chunks). Block 64 rois x 128 oc. Grid (6,28).
__global__ __launch_bounds__(256) void head_gemm_mfma(
    const u16* __restrict__ rf, const u16* __restrict__ wtHt,
    float* __restrict__ Gpart)
{
    __shared__ __align__(16) u16 As[64 * 40];
    __shared__ __align__(16) u16 Bs[128 * 40];
    const int tid = threadIdx.x;
    const int rb = blockIdx.x >> 1, ob = blockIdx.x & 1;
    const int split = blockIdx.y;
    const int lane = tid & 63, wid = tid >> 6;
    const int q = lane >> 4, m16 = lane & 15;
    const int wr = wid & 1, wo = wid >> 1;

    const int arl = tid >> 2, aqd = tid & 3;
    const u16* abase = rf + (long long)(rb * 64 + arl) * KRF + aqd * 8;
    const int bol0 = tid >> 2, bqd = tid & 3;       // Bs: two chunks
    const u16* bbase0 = wtHt + (long long)(ob * 128 + bol0) * KRF + bqd * 8;
    const u16* bbase1 = bbase0 + 64LL * KRF;

    f32x4 acc[2][4];
    #pragma unroll
    for (int i = 0; i < 2; ++i)
        #pragma unroll
        for (int j = 0; j < 4; ++j) acc[i][j] = (f32x4){0.f, 0.f, 0.f, 0.f};

    int k0 = split * CPS * 32;
    bf16x8 ra = *(const bf16x8*)(abase + k0);
    bf16x8 rb0 = *(const bf16x8*)(bbase0 + k0);
    bf16x8 rb1 = *(const bf16x8*)(bbase1 + k0);
    for (int cch = 0; cch < CPS; ++cch) {
        __syncthreads();
        *(bf16x8*)&As[arl * 40 + aqd * 8] = ra;
        *(bf16x8*)&Bs[bol0 * 40 + bqd * 8] = rb0;
        *(bf16x8*)&Bs[(64 + bol0) * 40 + bqd * 8] = rb1;
        __syncthreads();
        if (cch < CPS - 1) {
            int kn = k0 + (cch + 1) * 32;
            ra  = *(const bf16x8*)(abase + kn);
            rb0 = *(const bf16x8*)(bbase0 + kn);
            rb1 = *(const bf16x8*)(bbase1 + kn);
        }
        bf16x8 a[2], bb[4];
        #pragma unroll
        for (int rt = 0; rt < 2; ++rt)
            a[rt] = *(const bf16x8*)&As[(wr * 32 + rt * 16 + m16) * 40 + q * 8];
        #pragma unroll
        for (int ot = 0; ot < 4; ++ot)
            bb[ot] = *(const bf16x8*)&Bs[(wo * 64 + ot * 16 + m16) * 40 + q * 8];
        #pragma unroll
        for (int rt = 0; rt < 2; ++rt)
            #pragma unroll
            for (int ot = 0; ot < 4; ++ot)
                acc[rt][ot] = __builtin_amdgcn_mfma_f32_16x16x32_bf16(a[rt], bb[ot], acc[rt][ot], 0, 0, 0);
    }
    #pragma unroll
    for (int rt = 0; rt < 2; ++rt)
        #pragma unroll
        for (int ot = 0; ot < 4; ++ot) {
            int oc = ob * 128 + wo * 64 + ot * 16 + m16;
            #pragma unroll
            for (int rg = 0; rg < 4; ++rg) {
                int roi = rb * 64 + wr * 32 + rt * 16 + q * 4 + rg;
                Gpart[((long long)split * NROI + roi) * 256 + oc] = acc[rt][ot][rg];
            }
        }
}

__global__ __launch_bounds__(256) void reduce_G_kernel(
    const float* __restrict__ Gpart, float* __restrict__ G)
{
    int idx = blockIdx.x * 256 + threadIdx.x;
    float s = 0.f;
    #pragma unroll
    for (int sp = 0; sp < SPLITS; ++sp) s += Gpart[(long long)sp * NROI * 256 + idx];
    G[idx] = s;
}

// ---------------------------------------------------------------------------
// Fused tail: pair geometry + build_X + fc6 + fc7 + cls. Block = 64 pairs.
#define PHS 272
__global__ __launch_bounds__(256) void pair_head(
    const float* __restrict__ G, const float* __restrict__ d1,
    const float* __restrict__ d2, const float* __restrict__ wsum4,
    const float* __restrict__ hb,
    const u16* __restrict__ w6, const float* __restrict__ b6,
    const u16* __restrict__ w7, const float* __restrict__ b7,
    const float* __restrict__ cw, const float* __restrict__ cb,
    float* __restrict__ scores, float* __restrict__ labels,
    float* __restrict__ valid)
{
    __shared__ __align__(16) u16 bufA[64 * PHS];
    __shared__ __align__(16) u16 bufB[64 * PHS];
    __shared__ float Gs[2][256];
    __shared__ float ps[64][4];
    __shared__ float clw[256];

    const int tid = threadIdx.x;
    const int p0 = blockIdx.x * 64;
    const int r0 = p0 / MM;
    const int lane = tid & 63, w = tid >> 6;
    const int q = lane >> 4, m16 = lane & 15;

    clw[tid] = cw[tid];
    #pragma unroll
    for (int l = 0; l < 2; ++l) {
        int idx = tid + l * 256;
        int rr = idx >> 8, col = idx & 255;
        Gs[rr][col] = G[min(r0 + rr, NROI - 1) * 256 + col];
    }
    if (tid < 64) {
        int pair = p0 + tid;
        int b = pair / (MM * MM); int rem = pair % (MM * MM);
        int m1 = rem / MM, m2 = rem % MM;
        const float* rA = d1 + (long long)(b * MM + m1) * 10;
        const float* rB = d2 + (long long)(b * MM + m2) * 10;
        float v1 = rA[0], id1 = rA[1], cxa = rA[2], cya = rA[3], wa = rA[4], ha = rA[5];
        float v2 = rB[0], id2 = rB[1], cxb = rB[2], cyb = rB[3], wb = rB[4], hbv = rB[5];
        const float eps = 1e-6f;
        float ax1 = cxa - wa * 0.5f, ay1 = cya - ha * 0.5f;
        float ax2 = ax1 + wa,        ay2 = ay1 + ha;
        float bx1 = cxb - wb * 0.5f, by1 = cyb - hbv * 0.5f;
        float bx2 = bx1 + wb,        by2 = by1 + hbv;
        float ccx1 = (ax1 + ax2) * 0.5f, ccy1 = (ay1 + ay2) * 0.5f;
        float ww1 = fmaxf(ax2 - ax1, eps), hh1 = fmaxf(ay2 - ay1, eps);
        float ccx2 = (bx1 + bx2) * 0.5f, ccy2 = (by1 + by2) * 0.5f;
        float ww2 = fmaxf(bx2 - bx1, eps), hh2 = fmaxf(by2 - by1, eps);
        ps[tid][0] = (ccx2 - ccx1) / ww1;
        ps[tid][1] = (ccy2 - ccy1) / hh1;
        ps[tid][2] = logf(ww2 / ww1);
        ps[tid][3] = logf(hh2 / hh1);
        labels[pair] = (id1 == id2) ? 1.f : 0.f;
        valid[pair]  = (v1 != -1.f && v2 != -1.f) ? 1.f : 0.f;
    }
    __syncthreads();

    // build X tile [64 px][256 oc] into bufA
    #pragma unroll
    for (int it = 0; it < 16; ++it) {
        int idx = tid + it * 256;            // 4096 = 64 px * 64 oc4
        int px = idx >> 6, o4 = (idx & 63) * 4;
        int rl = (p0 + px) / MM - r0;
        f32x4 g = *(const f32x4*)&Gs[rl][o4];
        f32x4 hv = *(const f32x4*)&hb[o4];
        f32x4 p4 = *(const f32x4*)&ps[px][0];
        u16x4 pk;
        #pragma unroll
        for (int j = 0; j < 4; ++j) {
            f32x4 w4 = *(const f32x4*)&wsum4[(o4 + j) * 4];
            float v = g[j] + hv[j] + p4[0] * w4[0] + p4[1] * w4[1] + p4[2] * w4[2] + p4[3] * w4[3];
            pk[j] = f2bf(v);
        }
        *(u16x4*)&bufA[px * PHS + o4] = pk;
    }
    __syncthreads();

    // fc6: bufA -> bufB, then fc7: bufB -> bufA
    #pragma unroll
    for (int layer = 0; layer < 2; ++layer) {
        const u16* wgt = layer ? w7 : w6;
        const float* bs = layer ? b7 : b6;
        const u16* src = layer ? bufB : bufA;
        u16* dst = layer ? bufA : bufB;
        f32x4 acc[4][4];
        #pragma unroll
        for (int i = 0; i < 4; ++i)
            #pragma unroll
            for (int j = 0; j < 4; ++j) acc[i][j] = (f32x4){0.f, 0.f, 0.f, 0.f};
        #pragma unroll
        for (int kc = 0; kc < 8; ++kc) {
            bf16x8 a[4], bb[4];
            #pragma unroll
            for (int i = 0; i < 4; ++i)
                a[i] = *(const bf16x8*)&wgt[(w * 64 + i * 16 + m16) * 256 + kc * 32 + q * 8];
            #pragma unroll
            for (int pt = 0; pt < 4; ++pt)
                bb[pt] = *(const bf16x8*)&src[(pt * 16 + m16) * PHS + kc * 32 + q * 8];
            #pragma unroll
            for (int i = 0; i < 4; ++i)
                #pragma unroll
                for (int pt = 0; pt < 4; ++pt)
                    acc[i][pt] = __builtin_amdgcn_mfma_f32_16x16x32_bf16(a[i], bb[pt], acc[i][pt], 0, 0, 0);
        }
        #pragma unroll
        for (int i = 0; i < 4; ++i) {
            int oc4 = w * 64 + i * 16 + q * 4;
            f32x4 bv = *(const f32x4*)(bs + oc4);
            #pragma unroll
            for (int pt = 0; pt < 4; ++pt) {
                int px = pt * 16 + m16;
                f32x4 dd = acc[i][pt];
                u16x4 pk;
                #pragma unroll
                for (int rg = 0; rg < 4; ++rg)
                    pk[rg] = f2bf(fmaxf(dd[rg] + bv[rg], 0.f));
                *(u16x4*)&dst[px * PHS + oc4] = pk;
            }
        }
        __syncthreads();
    }

    // cls from bufA (holds H2)
    {
        int px = tid >> 2, qq = tid & 3;
        float acc = 0.f;
        #pragma unroll
        for (int k8 = 0; k8 < 8; ++k8) {
            bf16x8 hv = *(const bf16x8*)&bufA[px * PHS + qq * 64 + k8 * 8];
            #pragma unroll
            for (int e = 0; e < 8; ++e)
                acc += b2f((u16)hv[e]) * clw[qq * 64 + k8 * 8 + e];
        }
        acc += __shfl_xor(acc, 1, 64);
        acc += __shfl_xor(acc, 2, 64);
        if (qq == 0) scores[p0 + px] = acc + cb[0];
    }
}

// ---------------------------------------------------------------------------
extern "C" void kernel_launch(void* const* d_in, const int* in_sizes, int n_in,
                              void* d_out, int out_size, void* d_ws, size_t ws_size,
                              hipStream_t stream) {
    const float* corr   = (const float*)d_in[0];
    const float* det1   = (const float*)d_in[2];
    const float* det2   = (const float*)d_in[3];
    const float* c1w    = (const float*)d_in[4];
    const float* c1b    = (const float*)d_in[5];
    const float* c2w    = (const float*)d_in[6];
    const float* c2b    = (const float*)d_in[7];
    const float* c3w    = (const float*)d_in[8];
    const float* c3b    = (const float*)d_in[9];
    const float* hw     = (const float*)d_in[10];
    const float* hbias  = (const float*)d_in[11];
    const float* f6w    = (const float*)d_in[12];
    const float* f6b    = (const float*)d_in[13];
    const float* f7w    = (const float*)d_in[14];
    const float* f7b    = (const float*)d_in[15];
    const float* clsw   = (const float*)d_in[16];
    const float* clsb   = (const float*)d_in[17];
    float* out = (float*)d_out;

    char* base = (char*)d_ws;
    auto alloc = [&](size_t bytes) { char* p = base; base += (bytes + 255) & ~(size_t)255; return p; };

    const size_t ACTP_BYTES = (size_t)NB * 98 * 98 * 256 * 2;
    u16*   act1p = (u16*)  alloc(ACTP_BYTES);
    u16*   act2p = (u16*)  alloc(ACTP_BYTES);
    u16*   rel   = (u16*)  alloc((size_t)NB * PIX * 128 * 2);
    u16*   corrT = (u16*)  alloc((size_t)NB * PIX * 352 * 2);
    u16*   wt1f  = (u16*)  alloc((size_t)11 * 16 * 512 * 2);
    u16*   wt2f  = (u16*)  alloc((size_t)8 * 9 * 16 * 512 * 2);
    u16*   wt3f  = (u16*)  alloc((size_t)8 * 9 * 8 * 512 * 2);
    u16*   wtHt  = (u16*)  alloc((size_t)256 * KRF * 2);
    u16*   w6c   = (u16*)  alloc(256 * 256 * 2);
    u16*   w7c   = (u16*)  alloc(256 * 256 * 2);
    float* wsum4 = (float*)alloc(256 * 4 * 4);
    u16*   rf    = (u16*)  alloc((size_t)NROI * KRF * 2);
    float* Gpart = (float*)alloc((size_t)SPLITS * NROI * 256 * 4);
    float* G     = (float*)alloc(NROI * 256 * 4);

    float* scores_out = out;
    float* labels_out = out + NPAIR;
    float* valid_out  = out + 2 * NPAIR;

    zero_halo<<<388, 256, 0, stream>>>(act1p, act2p);
    prep_all<<<10596, 256, 0, stream>>>(c1w, c2w, c3w, hw, f6w, f7w,
                                        wt1f, wt2f, wt3f, wtHt, w6c, w7c, wsum4);
    cvt_corr<<<dim3(144, NB), 256, 0, stream>>>(corr, corrT);
    conv1_mfma<<<dim3(144, 2, NB), 256, 0, stream>>>(corrT, wt1f, c1b, act1p);
    conv3x3_mfma<256, true><<<dim3(72, 2, NB), 256, 0, stream>>>(act1p, wt2f, c2b, act2p);
    conv3x3_mfma<128, false><<<dim3(72, 1, NB), 256, 0, stream>>>(act2p, wt3f, c3b, rel);
    roi_align_cl<<<NROI, 256, 0, stream>>>(rel, det1, rf);
    head_gemm_mfma<<<dim3(6, SPLITS), 256, 0, stream>>>(rf, wtHt, Gpart);
    reduce_G_kernel<<<NROI, 256, 0, stream>>>(Gpart, G);
    pair_head<<<144, 256, 0, stream>>>(G, det1, det2, wsum4, hbias,
                                       w6c, f6b, w7c, f7b, clsw, clsb,
                                       scores_out, labels_out, valid_out);
}